// Round 1
// baseline (1149.411 us; speedup 1.0000x reference)
//
#include <hip/hip_runtime.h>
#include <math.h>

#define SLOPE 0.4f
#define EPS 1e-5f

__device__ __forceinline__ float leaky(float v) { return v >= 0.f ? v : SLOPE * v; }
__device__ __forceinline__ float dot4(float4 a, float4 b) {
    return a.x*b.x + a.y*b.y + a.z*b.z + a.w*b.w;
}

// ---------------------------------------------------------------------------
// FC: h[b][j] = leaky(dot(x[b,:], W[j,:]) + bias[j]), b<4, j<4096, K=40960
// grid 1024 blocks (4 j's each), 256 threads. Memory-bound on W (671 MB).
// ---------------------------------------------------------------------------
__global__ __launch_bounds__(256) void fc_kernel(const float* __restrict__ x,
                                                 const float* __restrict__ W,
                                                 const float* __restrict__ bias,
                                                 float* __restrict__ h) {
    const int j0 = blockIdx.x * 4;
    const int tid = threadIdx.x;
    const int K4 = 40960 / 4;
    float acc[4][4];  // [j_local][b]
#pragma unroll
    for (int a = 0; a < 4; ++a)
#pragma unroll
        for (int b = 0; b < 4; ++b) acc[a][b] = 0.f;

    const float4* x4 = (const float4*)x;
    for (int i = tid; i < K4; i += 256) {
        float4 xv[4];
#pragma unroll
        for (int b = 0; b < 4; ++b) xv[b] = x4[b * K4 + i];
#pragma unroll
        for (int a = 0; a < 4; ++a) {
            float4 wv = ((const float4*)(W + (size_t)(j0 + a) * 40960))[i];
#pragma unroll
            for (int b = 0; b < 4; ++b) acc[a][b] += dot4(wv, xv[b]);
        }
    }

    __shared__ float red[4][16];
    const int lane = tid & 63, wave = tid >> 6;
#pragma unroll
    for (int a = 0; a < 4; ++a)
#pragma unroll
        for (int b = 0; b < 4; ++b) {
            float v = acc[a][b];
            for (int d = 32; d > 0; d >>= 1) v += __shfl_down(v, d);
            if (lane == 0) red[wave][a * 4 + b] = v;
        }
    __syncthreads();
    if (tid < 16) {
        const int a = tid >> 2, b = tid & 3;
        float v = red[0][tid] + red[1][tid] + red[2][tid] + red[3][tid];
        const int j = j0 + a;
        h[b * 4096 + j] = leaky(v + bias[j]);
    }
}

// ---------------------------------------------------------------------------
// Generic 3x3 conv (pad 1) + InstanceNorm. Block = one (n, c_out) output
// plane; the IN group equals the block's plane, so mean/var is local.
// ---------------------------------------------------------------------------
__global__ __launch_bounds__(256) void conv_in_kernel(
    const float* __restrict__ in, float* __restrict__ out,
    const float* __restrict__ w, const float* __restrict__ bias,
    int C_in, int H_in, int W_in, int C_out, int H_out, int W_out, int stride) {
    __shared__ float s_in[4096];
    __shared__ float s_out[4096];
    __shared__ float s_w[288];
    __shared__ float s_red[8];
    __shared__ float s_mi[2];

    const int n = blockIdx.x / C_out;
    const int co = blockIdx.x % C_out;
    const int tid = threadIdx.x;

    const int in_sz = C_in * H_in * W_in;
    const float* inp = in + (size_t)n * in_sz;
    for (int i = tid; i < in_sz; i += 256) s_in[i] = inp[i];
    const int w_sz = C_in * 9;
    const float* wp = w + (size_t)co * w_sz;
    for (int i = tid; i < w_sz; i += 256) s_w[i] = wp[i];
    __syncthreads();

    const int S = H_out * W_out;
    const float bv = bias[co];
    float lsum = 0.f, lsq = 0.f;
    for (int p = tid; p < S; p += 256) {
        const int oy = p / W_out, ox = p % W_out;
        float acc = bv;
        for (int ci = 0; ci < C_in; ++ci) {
#pragma unroll
            for (int ky = 0; ky < 3; ++ky) {
                const int iy = oy * stride + ky - 1;
                if (iy < 0 || iy >= H_in) continue;
#pragma unroll
                for (int kx = 0; kx < 3; ++kx) {
                    const int ix = ox * stride + kx - 1;
                    if (ix < 0 || ix >= W_in) continue;
                    acc += s_in[(ci * H_in + iy) * W_in + ix] * s_w[ci * 9 + ky * 3 + kx];
                }
            }
        }
        s_out[p] = acc;
        lsum += acc;
        lsq += acc * acc;
    }

    const int lane = tid & 63, wave = tid >> 6;
    for (int d = 32; d > 0; d >>= 1) {
        lsum += __shfl_down(lsum, d);
        lsq += __shfl_down(lsq, d);
    }
    if (lane == 0) { s_red[wave] = lsum; s_red[4 + wave] = lsq; }
    __syncthreads();
    if (tid == 0) {
        const float sum = s_red[0] + s_red[1] + s_red[2] + s_red[3];
        const float sq  = s_red[4] + s_red[5] + s_red[6] + s_red[7];
        const float mean = sum / (float)S;
        const float var = sq / (float)S - mean * mean;
        s_mi[0] = mean;
        s_mi[1] = 1.0f / sqrtf(var + EPS);
    }
    __syncthreads();
    const float mean = s_mi[0], inv = s_mi[1];
    float* op = out + (size_t)(n * C_out + co) * S;
    for (int p = tid; p < S; p += 256) op[p] = (s_out[p] - mean) * inv;
}

// ---------------------------------------------------------------------------
// RNN layer-0 pre: pre0[t][b][j] = dot(seq[t][b], W_ih0[j]) + b_ih0[j]
// grid 64 (one per j), 256 threads, fully coalesced row reads.
// ---------------------------------------------------------------------------
__global__ __launch_bounds__(256) void pre0_kernel(const float* __restrict__ seq,
                                                   const float* __restrict__ Wih0,
                                                   const float* __restrict__ bih0,
                                                   float* __restrict__ pre0) {
    const int j = blockIdx.x;
    const int tid = threadIdx.x;
    const float4 wv = ((const float4*)(Wih0 + (size_t)j * 1024))[tid];
    float acc[8];
#pragma unroll
    for (int tb = 0; tb < 8; ++tb) {
        float4 xv = ((const float4*)(seq + (size_t)tb * 1024))[tid];
        acc[tb] = dot4(wv, xv);
    }
    __shared__ float red[4][8];
    const int lane = tid & 63, wave = tid >> 6;
#pragma unroll
    for (int tb = 0; tb < 8; ++tb) {
        float v = acc[tb];
        for (int d = 32; d > 0; d >>= 1) v += __shfl_down(v, d);
        if (lane == 0) red[wave][tb] = v;
    }
    __syncthreads();
    if (tid < 8) {
        const float v = red[0][tid] + red[1][tid] + red[2][tid] + red[3][tid];
        pre0[tid * 64 + j] = v + bih0[j];
    }
}

// ---------------------------------------------------------------------------
// 64-layer tanh RNN (T=2, B=4, H=64), single workgroup of 256 threads.
// Thread = (b, jh in 0..15, q in 0..3): handles j in {jh+16m}, k-chunk 16q..
// Full pre/state dots finished with width-4 shfl_xor butterfly.
// Output matmul (2,4,64)@(64,34)^T + leaky fused at the end.
// ---------------------------------------------------------------------------
__global__ __launch_bounds__(256) void rnn_kernel(const float* __restrict__ pre0,
                                                  const float* __restrict__ W_ihr,
                                                  const float* __restrict__ b_ihr,
                                                  const float* __restrict__ W_hh,
                                                  const float* __restrict__ b_hh,
                                                  const float* __restrict__ W_out,
                                                  const float* __restrict__ b_out,
                                                  float* __restrict__ out) {
    __shared__ __align__(16) float s_seq[2][4][64];

    const int tid = threadIdx.x;
    const int b = tid >> 6;          // 0..3
    const int lane = tid & 63;
    const int jh = lane >> 2;        // 0..15
    const int q = lane & 3;          // 0..3 (k-chunk / owner)
    const int j_own = jh + 16 * q;

    // ---- layer 0: pre comes from pre0 workspace ----
    {
        const float* bh = b_hh;      // layer 0
        const float* Wh = W_hh;      // layer 0
        const float p0 = pre0[(0 * 4 + b) * 64 + j_own];
        const float p1 = pre0[(1 * 4 + b) * 64 + j_own];
        const float bhv = bh[j_own];
        const float h1 = tanhf(p0 + bhv);
        s_seq[0][b][j_own] = h1;
        __syncthreads();

        float4 hv[4];
#pragma unroll
        for (int i = 0; i < 4; ++i)
            hv[i] = ((const float4*)&s_seq[0][b][0])[q * 4 + i];
        float acch[4];
#pragma unroll
        for (int m = 0; m < 4; ++m) {
            const int j = jh + 16 * m;
            const float4* wr = (const float4*)(Wh + j * 64) + q * 4;
            float a = 0.f;
#pragma unroll
            for (int i = 0; i < 4; ++i) a += dot4(wr[i], hv[i]);
            acch[m] = a;
        }
#pragma unroll
        for (int d = 1; d < 4; d <<= 1)
#pragma unroll
            for (int m = 0; m < 4; ++m) acch[m] += __shfl_xor(acch[m], d);
        const float h2 = tanhf(p1 + acch[q] + bhv);
        s_seq[1][b][j_own] = h2;
        __syncthreads();
    }

    // ---- layers 1..63 ----
    for (int l = 1; l < 64; ++l) {
        const float* Wi = W_ihr + (size_t)(l - 1) * 4096;
        const float* bi = b_ihr + (size_t)(l - 1) * 64;
        const float* Wh = W_hh + (size_t)l * 4096;
        const float* bh = b_hh + (size_t)l * 64;

        // pre partials: x chunks for both timesteps from LDS (broadcast)
        float4 xv[2][4];
#pragma unroll
        for (int t = 0; t < 2; ++t)
#pragma unroll
            for (int i = 0; i < 4; ++i)
                xv[t][i] = ((const float4*)&s_seq[t][b][0])[q * 4 + i];

        float accp[2][4];
#pragma unroll
        for (int t = 0; t < 2; ++t)
#pragma unroll
            for (int m = 0; m < 4; ++m) accp[t][m] = 0.f;
#pragma unroll
        for (int m = 0; m < 4; ++m) {
            const int j = jh + 16 * m;
            const float4* wr = (const float4*)(Wi + j * 64) + q * 4;
#pragma unroll
            for (int i = 0; i < 4; ++i) {
                const float4 wv = wr[i];
                accp[0][m] += dot4(wv, xv[0][i]);
                accp[1][m] += dot4(wv, xv[1][i]);
            }
        }
#pragma unroll
        for (int d = 1; d < 4; d <<= 1)
#pragma unroll
            for (int t = 0; t < 2; ++t)
#pragma unroll
                for (int m = 0; m < 4; ++m) accp[t][m] += __shfl_xor(accp[t][m], d);

        const float biv = bi[j_own];
        const float bhv = bh[j_own];
        const float pre0_own = accp[0][q] + biv;
        const float pre1_own = accp[1][q] + biv;

        __syncthreads();  // all s_seq reads of this layer done
        const float h1 = tanhf(pre0_own + bhv);
        s_seq[0][b][j_own] = h1;
        __syncthreads();  // h1 visible

        float4 hv[4];
#pragma unroll
        for (int i = 0; i < 4; ++i)
            hv[i] = ((const float4*)&s_seq[0][b][0])[q * 4 + i];
        float acch[4];
#pragma unroll
        for (int m = 0; m < 4; ++m) {
            const int j = jh + 16 * m;
            const float4* wr = (const float4*)(Wh + j * 64) + q * 4;
            float a = 0.f;
#pragma unroll
            for (int i = 0; i < 4; ++i) a += dot4(wr[i], hv[i]);
            acch[m] = a;
        }
#pragma unroll
        for (int d = 1; d < 4; d <<= 1)
#pragma unroll
            for (int m = 0; m < 4; ++m) acch[m] += __shfl_xor(acch[m], d);

        const float h2 = tanhf(pre1_own + acch[q] + bhv);
        s_seq[1][b][j_own] = h2;
        __syncthreads();
    }

    // ---- output: out[t][b][o] = leaky(dot(seq[t][b], W_out[o]) + b_out[o]) ----
    const int tb = tid >> 5;        // 0..7
    const int t = tb >> 2, bb = tb & 3;
    const int o0 = tid & 31;
    for (int o = o0; o < 34; o += 32) {
        float acc = b_out[o];
        const float* wr = W_out + o * 64;
        const float* xr = &s_seq[t][bb][0];
#pragma unroll
        for (int k = 0; k < 64; ++k) acc += xr[k] * wr[k];
        out[(t * 4 + bb) * 34 + o] = leaky(acc);
    }
}

// ---------------------------------------------------------------------------
extern "C" void kernel_launch(void* const* d_in, const int* in_sizes, int n_in,
                              void* d_out, int out_size, void* d_ws, size_t ws_size,
                              hipStream_t stream) {
    const float* x     = (const float*)d_in[0];
    const float* W_fc  = (const float*)d_in[1];
    const float* b_fc  = (const float*)d_in[2];
    const float* w0 = (const float*)d_in[3];
    const float* b0 = (const float*)d_in[4];
    const float* w1 = (const float*)d_in[5];
    const float* b1 = (const float*)d_in[6];
    const float* w2 = (const float*)d_in[7];
    const float* b2 = (const float*)d_in[8];
    const float* w3 = (const float*)d_in[9];
    const float* b3 = (const float*)d_in[10];
    const float* w4 = (const float*)d_in[11];
    const float* b4 = (const float*)d_in[12];
    const float* w5 = (const float*)d_in[13];
    const float* b5 = (const float*)d_in[14];
    const float* W_ih0 = (const float*)d_in[15];
    const float* b_ih0 = (const float*)d_in[16];
    const float* W_ihr = (const float*)d_in[17];
    const float* b_ihr = (const float*)d_in[18];
    const float* W_hh  = (const float*)d_in[19];
    const float* b_hh  = (const float*)d_in[20];
    const float* W_out = (const float*)d_in[21];
    const float* b_out = (const float*)d_in[22];
    float* out = (float*)d_out;

    float* ws   = (float*)d_ws;
    float* h_fc = ws;             // 16384 floats (4,4096)
    float* bufA = ws + 16384;     // 16384 floats
    float* bufB = ws + 32768;     // 16384 floats
    float* pre0 = ws + 49152;     // 512 floats (2,4,64)

    fc_kernel<<<1024, 256, 0, stream>>>(x, W_fc, b_fc, h_fc);

    // conv + instance-norm chain: (N, C_in, H_in, W_in) -> (N, C_out, H_out, W_out)
    conv_in_kernel<<<4,   256, 0, stream>>>(h_fc, bufA, w0, b0, 1, 4, 1024, 1, 4, 1024, 1);
    conv_in_kernel<<<16,  256, 0, stream>>>(bufA, bufB, w1, b1, 1, 4, 1024, 4, 2, 512, 2);
    conv_in_kernel<<<32,  256, 0, stream>>>(bufB, bufA, w2, b2, 4, 2, 512, 8, 1, 256, 2);
    conv_in_kernel<<<64,  256, 0, stream>>>(bufA, bufB, w3, b3, 8, 1, 256, 16, 1, 128, 2);
    conv_in_kernel<<<128, 256, 0, stream>>>(bufB, bufA, w4, b4, 16, 1, 128, 32, 1, 64, 2);
    conv_in_kernel<<<256, 256, 0, stream>>>(bufA, bufB, w5, b5, 32, 1, 64, 64, 1, 32, 2);

    // bufB now holds (4,64,1,32) == seq (2,4,1024) flat
    pre0_kernel<<<64, 256, 0, stream>>>(bufB, W_ih0, b_ih0, pre0);
    rnn_kernel<<<1, 256, 0, stream>>>(pre0, W_ihr, b_ihr, W_hh, b_hh,
                                      W_out, b_out, out);
}